// Round 14
// baseline (330.728 us; speedup 1.0000x reference)
//
#include <hip/hip_runtime.h>
#include <cstdint>

// ---------------------------------------------------------------------------
// AttentionBlock: B=2, C=512, H=W=64 (S=4096), 8 heads x 64 dim.
// I/O dtype: fp32. Internal: bf16 MFMA (16x16x32), fp32 accum.
// R14: attn is co-bound on LDS (~58%) and VALU (~55%); occupancy attacks are
// exhausted (3x neutral). Cut pipe work instead:
// (1) K-fragments loaded DIRECTLY global->regs (no Kl, no K-DMA): -28% LDS
//     traffic; next-iter K loads overlap exp/P/PV and drain with V's DMA.
//     VGPR ~100, capped 128 by launch_bounds(512,4) -> no spill (R12 lesson).
// (2) l computed by ones-MFMA on P-fragments (C/D col=query): deletes 32
//     v_add/iter + epilogue shuffles; l consistent with bf16 P used in PV.
// (3) 2-way j-split (R10-proven), V double-buffered, one barrier/iter.
// B^T-form MFMA: C[m][n] += A[m][k]*B[n][k]; C/D col(n)=lane&15, row(m)=lq*4+reg;
// A/B frag: row=lane&15, k=lq*8+j  (lq = lane>>4).
// ---------------------------------------------------------------------------

typedef __bf16 bf16x8 __attribute__((ext_vector_type(8)));
typedef __bf16 bf16x4 __attribute__((ext_vector_type(4)));
typedef float f32x4 __attribute__((ext_vector_type(4)));
typedef unsigned short u16x8 __attribute__((ext_vector_type(8)));
typedef unsigned short u16x4 __attribute__((ext_vector_type(4)));

#define AS1 __attribute__((address_space(1)))
#define AS3 __attribute__((address_space(3)))

__device__ __forceinline__ void async16(const void* g, void* l) {
  __builtin_amdgcn_global_load_lds((const AS1 void*)g, (AS3 void*)l, 16, 0, 0);
}

__device__ __forceinline__ uint16_t f2bf(float f) {
  union { float f; uint32_t u; } a;
  a.f = f;
  uint32_t r = a.u + 0x7fffu + ((a.u >> 16) & 1u);  // RNE
  return (uint16_t)(r >> 16);
}

__device__ __forceinline__ float bf2f(uint16_t u) {
  union { uint32_t u; float f; } a;
  a.u = (uint32_t)u << 16;
  return a.f;
}

// ---------------------------------------------------------------------------
// prep: z=0..3 -> transpose+convert x/ctx [C][S] fp32 -> [S][C] bf16;
//       z=4    -> convert the 4 weight matrices fp32 -> bf16 (flat).
// ---------------------------------------------------------------------------
__global__ __launch_bounds__(256) void prep(
    const float* __restrict__ x, const float* __restrict__ ctx,
    const float* __restrict__ Wq, const float* __restrict__ Wk,
    const float* __restrict__ Wv, const float* __restrict__ Wo,
    uint16_t* __restrict__ xT, uint16_t* __restrict__ cT,
    uint16_t* __restrict__ Wqb, uint16_t* __restrict__ Wkb,
    uint16_t* __restrict__ Wvb, uint16_t* __restrict__ Wob) {
  const int zz = blockIdx.z;
  const int t = threadIdx.x;
  if (zz == 4) {
    const float* W[4] = {Wq, Wk, Wv, Wo};
    uint16_t* O[4] = {Wqb, Wkb, Wvb, Wob};
    const int blk = blockIdx.x + 64 * blockIdx.y;      // 0..511
    const size_t base = (size_t)blk * 2048 + (size_t)t * 8;
    const int w = (int)(base >> 18);                   // 512*512 = 2^18
    const size_t off = base & 262143;
    float4 v0 = *(const float4*)&W[w][off];
    float4 v1 = *(const float4*)&W[w][off + 4];
    u16x8 o = {f2bf(v0.x), f2bf(v0.y), f2bf(v0.z), f2bf(v0.w),
               f2bf(v1.x), f2bf(v1.y), f2bf(v1.z), f2bf(v1.w)};
    *(u16x8*)&O[w][off] = o;
    return;
  }
  const float* src = (zz < 2 ? x : ctx) + (size_t)(zz & 1) * 512 * 4096;
  uint16_t* dst = (zz < 2 ? xT : cT) + (size_t)(zz & 1) * 4096 * 512;
  const int s0 = blockIdx.x * 64, c0 = blockIdx.y * 64;
  __shared__ uint16_t tile[64][80];
  for (int p = 0; p < 2; ++p) {
    int u = p * 256 + t;
    int r = u >> 3, cg = (u & 7) * 8;
    const float* sp = &src[(size_t)(c0 + r) * 4096 + s0 + cg];
    float4 v0 = *(const float4*)sp;
    float4 v1 = *(const float4*)(sp + 4);
    u16x8 o = {f2bf(v0.x), f2bf(v0.y), f2bf(v0.z), f2bf(v0.w),
               f2bf(v1.x), f2bf(v1.y), f2bf(v1.z), f2bf(v1.w)};
    *(u16x8*)&tile[r][cg] = o;
  }
  __syncthreads();
  for (int p = 0; p < 2; ++p) {
    int u = p * 256 + t;
    int sr = u >> 3, cg = (u & 7) * 8;
    u16x8 v;
    for (int j = 0; j < 8; ++j) v[j] = tile[cg + j][sr];
    *(u16x8*)&dst[(size_t)(s0 + sr) * 512 + c0 + cg] = v;
  }
}

// ---------------------------------------------------------------------------
// Fused QKV projection (R9-passing). blockIdx.z = sel*2 + batch.
// C[m][n] = (sum_k A[m][k]*B[n][k] + bias) * os, stored C[col*ldC + row].
// ---------------------------------------------------------------------------
struct QkvArgs {
  const uint16_t* A[3]; long long sA[3];
  const uint16_t* B[3]; long long sB[3];
  uint16_t* C[3];       long long sC[3];
  const float* bias[3];
  float os[3];
  long long ldC[3]; int lx[3]; int brow[3];
};

__global__ __launch_bounds__(256) void gemm_qkv(QkvArgs ga) {
  constexpr int K = 512;
  __shared__ uint16_t At[128 * 32];
  __shared__ uint16_t Bt[128 * 32];
  const int t = threadIdx.x, lane = t & 63, wave = t >> 6;
  const int lr = lane & 15, lq = lane >> 4;
  const int wm = (wave >> 1) * 64, wn = (wave & 1) * 64;
  const int sel = blockIdx.z >> 1, bat = blockIdx.z & 1;
  const int lx = ga.lx[sel], brow = ga.brow[sel];
  const long long ldC = ga.ldC[sel];
  const float os = ga.os[sel];
  const int n0 = (blockIdx.x & ((1 << lx) - 1)) * 128;
  const int m0 = (blockIdx.x >> lx) * 128;
  const uint16_t* A = ga.A[sel] + (size_t)bat * ga.sA[sel];
  const uint16_t* B = ga.B[sel] + (size_t)bat * ga.sB[sel];
  const float* bias = ga.bias[sel];
  f32x4 acc[4][4] = {};
  for (int k0 = 0; k0 < K; k0 += 32) {
    __syncthreads();
    for (int p = 0; p < 2; ++p) {
      int u = p * 256 + t;
      int r = u >> 2, c = (u & 3) * 8;
      async16(&A[(size_t)(m0 + r) * K + k0 + c], &At[p * 2048 + wave * 512]);
      async16(&B[(size_t)(n0 + r) * K + k0 + c], &Bt[p * 2048 + wave * 512]);
    }
    __builtin_amdgcn_s_waitcnt(0);
    __syncthreads();
    bf16x8 af[4], bfr[4];
    for (int i = 0; i < 4; ++i)
      af[i] = *(const bf16x8*)&At[(wm + i * 16 + lr) * 32 + lq * 8];
    for (int j = 0; j < 4; ++j)
      bfr[j] = *(const bf16x8*)&Bt[(wn + j * 16 + lr) * 32 + lq * 8];
    for (int i = 0; i < 4; ++i)
      for (int j = 0; j < 4; ++j)
        acc[i][j] = __builtin_amdgcn_mfma_f32_16x16x32_bf16(af[i], bfr[j], acc[i][j], 0, 0, 0);
  }
  uint16_t* C = ga.C[sel] + (size_t)bat * ga.sC[sel];
  for (int i = 0; i < 4; ++i)
    for (int j = 0; j < 4; ++j) {
      int row = m0 + wm + i * 16 + lq * 4;
      int col = n0 + wn + j * 16 + lr;
      float bc = brow ? 0.f : bias[col];
      u16x4 o;
      for (int r = 0; r < 4; ++r) {
        float val = (acc[i][j][r] + (brow ? bias[row + r] : bc)) * os;
        o[r] = f2bf(val);
      }
      *(u16x4*)&C[(size_t)col * ldC + row] = o;
    }
}

// ---------------------------------------------------------------------------
// Output projection with fused 2-way combine. A = (Ap0+Ap1)/(l0+l1) built
// in-register during staging. m/n-swapped: m=s contiguous -> float4 stores
// into Y[c][s]. 128(m)x64(n) tiles, grid (8, 32, 2).
// ---------------------------------------------------------------------------
__global__ __launch_bounds__(256) void gemm_out(
    const uint16_t* __restrict__ Ap, const float* __restrict__ Lp,
    const uint16_t* __restrict__ Wo, float* __restrict__ Y,
    const float* __restrict__ bias) {
  constexpr int K = 512, S = 4096, E = 512;
  __shared__ uint16_t At[128 * 32];
  __shared__ uint16_t Bt[64 * 32];
  const int t = threadIdx.x, lane = t & 63, wave = t >> 6;
  const int lr = lane & 15, lq = lane >> 4;
  const int wm = (wave & 1) * 64, wn = (wave >> 1) * 32;
  const int m0 = blockIdx.y * 128, n0 = blockIdx.x * 64;
  const int b = blockIdx.z;
  const size_t bOff = (size_t)b * S * E;
  const size_t HALF = (size_t)2 * S * E;  // jh stride in Ap
  f32x4 acc[4][2] = {};
  for (int k0 = 0; k0 < K; k0 += 32) {
    const int h = k0 >> 6;  // head is uniform within a 32-wide k-chunk
    const float* l0p = &Lp[((size_t)(0 + b) * 8 + h) * S];
    const float* l1p = &Lp[((size_t)(2 + b) * 8 + h) * S];
    __syncthreads();
    for (int p = 0; p < 2; ++p) {
      int u = p * 256 + t;
      int r = u >> 2, c = (u & 3) * 8;
      size_t off = bOff + (size_t)(m0 + r) * E + k0 + c;
      u16x8 a0 = *(const u16x8*)&Ap[off];
      u16x8 a1 = *(const u16x8*)&Ap[HALF + off];
      float inv = 1.f / (l0p[m0 + r] + l1p[m0 + r]);
      u16x8 o;
      for (int q = 0; q < 8; ++q)
        o[q] = f2bf((bf2f(a0[q]) + bf2f(a1[q])) * inv);
      *(u16x8*)&At[r * 32 + c] = o;
    }
    {
      int r = t >> 2, c = (t & 3) * 8;
      async16(&Wo[(size_t)(n0 + r) * K + k0 + c], &Bt[wave * 512]);
    }
    __builtin_amdgcn_s_waitcnt(0);
    __syncthreads();
    bf16x8 af[4], bfr[2];
    for (int i = 0; i < 4; ++i)
      af[i] = *(const bf16x8*)&At[(wm + i * 16 + lr) * 32 + lq * 8];
    for (int j = 0; j < 2; ++j)
      bfr[j] = *(const bf16x8*)&Bt[(wn + j * 16 + lr) * 32 + lq * 8];
    for (int i = 0; i < 4; ++i)
      for (int j = 0; j < 2; ++j)
        acc[i][j] = __builtin_amdgcn_mfma_f32_16x16x32_bf16(af[i], bfr[j], acc[i][j], 0, 0, 0);
  }
  float* Cf = Y + (size_t)b * 512 * 4096;
  for (int i = 0; i < 4; ++i)
    for (int j = 0; j < 2; ++j) {
      int row = m0 + wm + i * 16 + lq * 4;  // s (contiguous)
      int col = n0 + wn + j * 16 + lr;      // c
      float bb = bias[col];
      float4 o = {acc[i][j][0] + bb, acc[i][j][1] + bb,
                  acc[i][j][2] + bb, acc[i][j][3] + bb};
      *(float4*)&Cf[(size_t)col * 4096 + row] = o;
    }
}

// ---------------------------------------------------------------------------
// Flash attention half-range pass. Q pre-scaled by SCALE*log2e.
// 512 threads = 8 waves, q-tile 256. grid (S/256, 8, 4): z = jh*2 + b.
// K-fragments loaded DIRECTLY from global into registers (no Kl/K-DMA);
// V double-buffered in LDS via DMA; one waitcnt(0)+barrier per iter.
// l accumulated by ones-MFMA on the P fragments (C/D col = query = lr).
// Writes UNNORMALIZED partial O^T (bf16, [jh][B][S][E]) + partial l (fp32).
// V LDS tile XOR-chunk-swizzled: 16B chunk c of row r stored at c^(r&7).
// LDS: Vl 16K + Pl 36K = 52 KB.
// ---------------------------------------------------------------------------
__global__ __launch_bounds__(512, 4) void attn128(
    const uint16_t* __restrict__ Q, const uint16_t* __restrict__ K,
    const uint16_t* __restrict__ Vt, uint16_t* __restrict__ Ap,
    float* __restrict__ Lp) {
  constexpr int S = 4096, E = 512;
  const int b = blockIdx.z & 1, jh = blockIdx.z >> 1;
  const int h = blockIdx.y;
  const int i0 = blockIdx.x * 256;
  const int t = threadIdx.x, lane = t & 63, wave = t >> 6;
  const int lr = lane & 15, lq = lane >> 4;
  const size_t qkB = (size_t)b * S * E;
  const size_t vB = (size_t)b * E * S;
  __shared__ uint16_t Vl[2][64 * 64];     // [buf][d][j], chunk-swizzled rows
  __shared__ __bf16 Pl[8 * 2 * 16 * 72];  // [wave][g][i 16][j 64+8pad]

  const int qbase = i0 + wave * 32;
  bf16x8 qf[2][2];
  for (int g = 0; g < 2; ++g) {
    const size_t qo = qkB + (size_t)(qbase + g * 16 + lr) * E + h * 64 + lq * 8;
    qf[g][0] = *(const bf16x8*)&Q[qo];
    qf[g][1] = *(const bf16x8*)&Q[qo + 32];
  }
  bf16x8 ones;
  for (int i = 0; i < 8; ++i) ones[i] = (__bf16)1.0f;
  f32x4 lacc[2] = {};       // ones-MFMA row-sum accum (col = query = lr)
  f32x4 accOT[2][4] = {};   // O^T accum: col = query = lr, row = d
  const int swz = (lr & 7);
  const int srr = t >> 3, ssc = ((t & 7) ^ (srr & 7)) * 8;  // V staging row/col

  const int jbeg = jh * (S / 2), jend = jbeg + S / 2;
  // K fragment base for this lane: row = j0 + jn*16 + lr, chunks lq*8, +32
  const uint16_t* Kb_ = &K[qkB + (size_t)(jbeg + lr) * E + h * 64 + lq * 8];

  // prolog: stage V(jbeg) into buf 0; load K(jbeg) fragments direct
  async16(&Vt[vB + (size_t)(h * 64 + srr) * S + jbeg + ssc], &Vl[0][wave * 512]);
  bf16x8 ka[4][2];
  for (int jn = 0; jn < 4; ++jn) {
    ka[jn][0] = *(const bf16x8*)&Kb_[(size_t)(jn * 16) * E];
    ka[jn][1] = *(const bf16x8*)&Kb_[(size_t)(jn * 16) * E + 32];
  }
  __builtin_amdgcn_s_waitcnt(0);
  __syncthreads();

  int cur = 0;
  for (int j0 = jbeg; j0 < jend; j0 += 64) {
    const bool more = (j0 + 64 < jend);
    // stage next V tile into alt buffer — flies across this iter's compute
    if (more)
      async16(&Vt[vB + (size_t)(h * 64 + srr) * S + j0 + 64 + ssc], &Vl[cur ^ 1][wave * 512]);
    // S^T tile: C[m=j][n=i] = sum_d K[j][d] Q[i][d]; K-frags from registers
    f32x4 svt[2][4];
    for (int jn = 0; jn < 4; ++jn)
      for (int g = 0; g < 2; ++g) {
        f32x4 z = {0.f, 0.f, 0.f, 0.f};
        z = __builtin_amdgcn_mfma_f32_16x16x32_bf16(ka[jn][0], qf[g][0], z, 0, 0, 0);
        z = __builtin_amdgcn_mfma_f32_16x16x32_bf16(ka[jn][1], qf[g][1], z, 0, 0, 0);
        svt[g][jn] = z;
      }
    // issue next iter's K fragment loads (ka consumed by S^T above);
    // they fly during exp/P/PV and drain at the iter-end waitcnt.
    if (more) {
      const uint16_t* Kn = Kb_ + (size_t)(j0 + 64 - jbeg) * E;
      for (int jn = 0; jn < 4; ++jn) {
        ka[jn][0] = *(const bf16x8*)&Kn[(size_t)(jn * 16) * E];
        ka[jn][1] = *(const bf16x8*)&Kn[(size_t)(jn * 16) * E + 32];
      }
    }
    // P = exp2(s); write BOTH g's P to per-g regions, then read fragments
    for (int g = 0; g < 2; ++g) {
      __bf16* pr = &Pl[((wave * 2 + g) * 16 + lr) * 72];
      for (int jn = 0; jn < 4; ++jn) {
        f32x4 p;
        for (int r = 0; r < 4; ++r) p[r] = exp2f(svt[g][jn][r]);
        bf16x4 pk;
        for (int r = 0; r < 4; ++r) pk[r] = (__bf16)p[r];
        *(bf16x4*)&pr[jn * 16 + lq * 4] = pk;
      }
    }
    bf16x8 pa[2][2];
    for (int g = 0; g < 2; ++g) {
      const __bf16* pr = &Pl[((wave * 2 + g) * 16 + lr) * 72];
      pa[g][0] = *(const bf16x8*)&pr[lq * 8];
      pa[g][1] = *(const bf16x8*)&pr[32 + lq * 8];
    }
    // PV in O^T form (A = Vt rows d, B = P); ones-MFMA accumulates l
    for (int dn = 0; dn < 4; ++dn) {
      const int row = dn * 16 + lr;
      const int c0 = (lq ^ swz) * 8;
      bf16x8 v0 = *(const bf16x8*)&Vl[cur][row * 64 + c0];
      bf16x8 v1 = *(const bf16x8*)&Vl[cur][row * 64 + (c0 ^ 32)];
      for (int g = 0; g < 2; ++g) {
        accOT[g][dn] = __builtin_amdgcn_mfma_f32_16x16x32_bf16(v0, pa[g][0], accOT[g][dn], 0, 0, 0);
        accOT[g][dn] = __builtin_amdgcn_mfma_f32_16x16x32_bf16(v1, pa[g][1], accOT[g][dn], 0, 0, 0);
      }
    }
    for (int g = 0; g < 2; ++g) {
      lacc[g] = __builtin_amdgcn_mfma_f32_16x16x32_bf16(ones, pa[g][0], lacc[g], 0, 0, 0);
      lacc[g] = __builtin_amdgcn_mfma_f32_16x16x32_bf16(ones, pa[g][1], lacc[g], 0, 0, 0);
    }
    // drain next V DMA + next K loads; barrier also fences Pl WAR across iters
    __builtin_amdgcn_s_waitcnt(0);
    __syncthreads();
    cur ^= 1;
  }
  // epilogue: l = lacc[g][0] (all rows/lanes of a col identical); store
  uint16_t* Aph = Ap + (size_t)jh * 2 * S * E;
  float* Lph = Lp + ((size_t)(jh * 2 + b) * 8 + h) * S;
  for (int g = 0; g < 2; ++g) {
    if (lane < 16) Lph[qbase + g * 16 + lr] = lacc[g][0];
    const size_t row = qbase + g * 16 + lr;
    for (int dn = 0; dn < 4; ++dn) {
      u16x4 o;
      for (int r = 0; r < 4; ++r) o[r] = f2bf(accOT[g][dn][r]);
      *(u16x4*)&Aph[qkB + row * E + h * 64 + dn * 16 + lq * 4] = o;
    }
  }
}

// ---------------------------------------------------------------------------
extern "C" void kernel_launch(void* const* d_in, const int* in_sizes, int n_in,
                              void* d_out, int out_size, void* d_ws, size_t ws_size,
                              hipStream_t stream) {
  const float* x   = (const float*)d_in[0];
  const float* ctx = (const float*)d_in[1];
  const float* Wq  = (const float*)d_in[2];
  const float* bq  = (const float*)d_in[3];
  const float* Wk  = (const float*)d_in[4];
  const float* bk  = (const float*)d_in[5];
  const float* Wv  = (const float*)d_in[6];
  const float* bv  = (const float*)d_in[7];
  const float* Wo  = (const float*)d_in[8];
  const float* bo  = (const float*)d_in[9];
  float* out = (float*)d_out;

  const size_t SZ = (size_t)2 * 4096 * 512;
  uint16_t* xT = (uint16_t*)d_ws;
  uint16_t* cT = xT + SZ;
  uint16_t* Qb = cT + SZ;
  uint16_t* Kb = Qb + SZ;
  uint16_t* Vb = Kb + SZ;    // Vt layout [B][E][S]
  uint16_t* Wqb = Vb + SZ;
  uint16_t* Wkb = Wqb + 512 * 512;
  uint16_t* Wvb = Wkb + 512 * 512;
  uint16_t* Wob = Wvb + 512 * 512;
  uint16_t* Ap  = Wob + 512 * 512;            // partial O, [2][B][S][E] bf16
  float*    Lp  = (float*)(Ap + 2 * SZ);      // partial l, [2][B][8][S] fp32
  const long long sIn = 4096LL * 512LL;
  const float slh = 0.125f * 1.44269504088896f;  // SCALE * log2(e)

  prep<<<dim3(64, 8, 5), 256, 0, stream>>>(x, ctx, Wq, Wk, Wv, Wo,
                                           xT, cT, Wqb, Wkb, Wvb, Wob);
  // fused Q,K,V projections (m/n swapped for vector stores); Q pre-scaled
  QkvArgs qkv = {
      {Wqb, Wkb, cT}, {0, 0, sIn},          // A
      {xT, cT, Wvb}, {sIn, sIn, 0},         // B
      {Qb, Kb, Vb}, {sIn, sIn, sIn},        // C
      {bq, bk, bv},
      {slh, 1.f, 1.f},
      {512, 512, 4096},                      // ldC
      {5, 5, 2},                             // lx = log2(n-tiles)
      {1, 1, 0}};                            // brow
  gemm_qkv<<<dim3(128, 1, 6), 256, 0, stream>>>(qkv);
  attn128<<<dim3(16, 8, 4), 512, 0, stream>>>(Qb, Kb, Vb, Ap, Lp);
  // Y[c][s] = sum_e ((Ap0+Ap1)/(l0+l1))[s][e] * Wo[c][e] + bo[c]
  gemm_out<<<dim3(8, 32, 2), 256, 0, stream>>>(Ap, Lp, Wob, out, bo);
}

// Round 15
// 246.534 us; speedup vs baseline: 1.3415x; 1.3415x over previous
//
#include <hip/hip_runtime.h>
#include <cstdint>

// ---------------------------------------------------------------------------
// AttentionBlock: B=2, C=512, H=W=64 (S=4096), 8 heads x 64 dim.
// I/O dtype: fp32. Internal: bf16 MFMA (16x16x32), fp32 accum.
// R15 = exact revert to the best-measured configuration (R10, 248.7 us):
// - attn128: 512-thread blocks (8 waves), q-tile 256, 2-way j-split,
//   K/V double-buffered LDS via global_load_lds (coalesced staging — R14
//   showed per-lane direct K loads serialize on 1KB-strided cache lines),
//   one waitcnt(0)+barrier per iter, streaming softmax (Q pre-scaled),
//   unnormalized partial O^T + partial l to workspace.
// - gemm_qkv: fused Q/K/V projections, m/n swapped for u16x4 stores.
// - gemm_out: m/n swapped, float4 stores; separate attn_combine kernel.
// Post-R14 accounting: total ~= 75us harness restore/poison (invariant) +
// ~55us near-floor small kernels + ~119us attn plateau (VALU/LDS co-bound,
// 4x the 29us MFMA floor; occupancy & pipelining attacks exhausted).
// B^T-form MFMA: C[m][n] += A[m][k]*B[n][k]; C/D col(n)=lane&15, row(m)=lq*4+reg;
// A/B frag: row=lane&15, k=lq*8+j  (lq = lane>>4).
// ---------------------------------------------------------------------------

typedef __bf16 bf16x8 __attribute__((ext_vector_type(8)));
typedef __bf16 bf16x4 __attribute__((ext_vector_type(4)));
typedef float f32x4 __attribute__((ext_vector_type(4)));
typedef unsigned short u16x8 __attribute__((ext_vector_type(8)));
typedef unsigned short u16x4 __attribute__((ext_vector_type(4)));

#define AS1 __attribute__((address_space(1)))
#define AS3 __attribute__((address_space(3)))

__device__ __forceinline__ void async16(const void* g, void* l) {
  __builtin_amdgcn_global_load_lds((const AS1 void*)g, (AS3 void*)l, 16, 0, 0);
}

__device__ __forceinline__ uint16_t f2bf(float f) {
  union { float f; uint32_t u; } a;
  a.f = f;
  uint32_t r = a.u + 0x7fffu + ((a.u >> 16) & 1u);  // RNE
  return (uint16_t)(r >> 16);
}

__device__ __forceinline__ float bf2f(uint16_t u) {
  union { uint32_t u; float f; } a;
  a.u = (uint32_t)u << 16;
  return a.f;
}

// ---------------------------------------------------------------------------
__global__ __launch_bounds__(256) void cvt_w(
    const float* __restrict__ W0, const float* __restrict__ W1,
    const float* __restrict__ W2, const float* __restrict__ W3,
    uint16_t* __restrict__ O0, uint16_t* __restrict__ O1,
    uint16_t* __restrict__ O2, uint16_t* __restrict__ O3) {
  const float* W[4] = {W0, W1, W2, W3};
  uint16_t* O[4] = {O0, O1, O2, O3};
  const int w = blockIdx.y;
  const int i = (blockIdx.x * 256 + threadIdx.x) * 4;
  float4 v = *(const float4*)&W[w][i];
  u16x4 o = {f2bf(v.x), f2bf(v.y), f2bf(v.z), f2bf(v.w)};
  *(u16x4*)&O[w][i] = o;
}

// ---------------------------------------------------------------------------
// Transpose+convert [C=512][S=4096] fp32 -> [S][C] bf16, x and context.
// ---------------------------------------------------------------------------
__global__ __launch_bounds__(256) void transpose_cs(
    const float* __restrict__ x, const float* __restrict__ ctx,
    uint16_t* __restrict__ xT, uint16_t* __restrict__ cT) {
  const int zz = blockIdx.z;
  const float* src = (zz < 2 ? x : ctx) + (size_t)(zz & 1) * 512 * 4096;
  uint16_t* dst = (zz < 2 ? xT : cT) + (size_t)(zz & 1) * 4096 * 512;
  const int s0 = blockIdx.x * 64, c0 = blockIdx.y * 64;
  __shared__ uint16_t tile[64][80];
  const int t = threadIdx.x;
  for (int p = 0; p < 2; ++p) {
    int u = p * 256 + t;
    int r = u >> 3, cg = (u & 7) * 8;
    const float* sp = &src[(size_t)(c0 + r) * 4096 + s0 + cg];
    float4 v0 = *(const float4*)sp;
    float4 v1 = *(const float4*)(sp + 4);
    u16x8 o = {f2bf(v0.x), f2bf(v0.y), f2bf(v0.z), f2bf(v0.w),
               f2bf(v1.x), f2bf(v1.y), f2bf(v1.z), f2bf(v1.w)};
    *(u16x8*)&tile[r][cg] = o;
  }
  __syncthreads();
  for (int p = 0; p < 2; ++p) {
    int u = p * 256 + t;
    int sr = u >> 3, cg = (u & 7) * 8;
    u16x8 v;
    for (int j = 0; j < 8; ++j) v[j] = tile[cg + j][sr];
    *(u16x8*)&dst[(size_t)(s0 + sr) * 512 + c0 + cg] = v;
  }
}

// ---------------------------------------------------------------------------
// Fused QKV projection. blockIdx.z = sel*2 + batch, sel in {0:Q, 1:K, 2:V}.
// C[m][n] = (sum_k A[m][k]*B[n][k] + bias) * os, stored at C[col*ldC + row]
// (row = m is the contiguous dim -> u16x4 stores).
// Q/K: A=W (m=e), B=xT/cT (n=s), out Q[s][e] (ldC=512), bias by row.
// V:   A=cT (m=s), B=Wv (n=e), out Vt[e][s] (ldC=4096), bias by col.
// ---------------------------------------------------------------------------
struct QkvArgs {
  const uint16_t* A[3]; long long sA[3];
  const uint16_t* B[3]; long long sB[3];
  uint16_t* C[3];       long long sC[3];
  const float* bias[3];
  float os[3];
  long long ldC[3]; int lx[3]; int brow[3];
};

__global__ __launch_bounds__(256) void gemm_qkv(QkvArgs ga) {
  constexpr int K = 512;
  __shared__ uint16_t At[128 * 32];
  __shared__ uint16_t Bt[128 * 32];
  const int t = threadIdx.x, lane = t & 63, wave = t >> 6;
  const int lr = lane & 15, lq = lane >> 4;
  const int wm = (wave >> 1) * 64, wn = (wave & 1) * 64;
  const int sel = blockIdx.z >> 1, bat = blockIdx.z & 1;
  const int lx = ga.lx[sel], brow = ga.brow[sel];
  const long long ldC = ga.ldC[sel];
  const float os = ga.os[sel];
  const int n0 = (blockIdx.x & ((1 << lx) - 1)) * 128;
  const int m0 = (blockIdx.x >> lx) * 128;
  const uint16_t* A = ga.A[sel] + (size_t)bat * ga.sA[sel];
  const uint16_t* B = ga.B[sel] + (size_t)bat * ga.sB[sel];
  const float* bias = ga.bias[sel];
  f32x4 acc[4][4] = {};
  for (int k0 = 0; k0 < K; k0 += 32) {
    __syncthreads();
    for (int p = 0; p < 2; ++p) {
      int u = p * 256 + t;
      int r = u >> 2, c = (u & 3) * 8;
      async16(&A[(size_t)(m0 + r) * K + k0 + c], &At[p * 2048 + wave * 512]);
      async16(&B[(size_t)(n0 + r) * K + k0 + c], &Bt[p * 2048 + wave * 512]);
    }
    __builtin_amdgcn_s_waitcnt(0);
    __syncthreads();
    bf16x8 af[4], bfr[4];
    for (int i = 0; i < 4; ++i)
      af[i] = *(const bf16x8*)&At[(wm + i * 16 + lr) * 32 + lq * 8];
    for (int j = 0; j < 4; ++j)
      bfr[j] = *(const bf16x8*)&Bt[(wn + j * 16 + lr) * 32 + lq * 8];
    for (int i = 0; i < 4; ++i)
      for (int j = 0; j < 4; ++j)
        acc[i][j] = __builtin_amdgcn_mfma_f32_16x16x32_bf16(af[i], bfr[j], acc[i][j], 0, 0, 0);
  }
  uint16_t* C = ga.C[sel] + (size_t)bat * ga.sC[sel];
  for (int i = 0; i < 4; ++i)
    for (int j = 0; j < 4; ++j) {
      int row = m0 + wm + i * 16 + lq * 4;
      int col = n0 + wn + j * 16 + lr;
      float bc = brow ? 0.f : bias[col];
      u16x4 o;
      for (int r = 0; r < 4; ++r) {
        float val = (acc[i][j][r] + (brow ? bias[row + r] : bc)) * os;
        o[r] = f2bf(val);
      }
      *(u16x4*)&C[(size_t)col * ldC + row] = o;
    }
}

// ---------------------------------------------------------------------------
// Output projection, m/n-swapped: A=Ob (m=s), B=Wo (n=c), Y[c][s] fp32 via
// float4 stores. 128(m)x64(n) tiles -> grid (8, 32, 2) = 512 blocks.
// ---------------------------------------------------------------------------
__global__ __launch_bounds__(256) void gemm_out(
    const uint16_t* __restrict__ Ob, long long sA,
    const uint16_t* __restrict__ Wo, float* __restrict__ Y, long long sC,
    const float* __restrict__ bias) {
  constexpr int K = 512;
  __shared__ uint16_t At[128 * 32];
  __shared__ uint16_t Bt[64 * 32];
  const int t = threadIdx.x, lane = t & 63, wave = t >> 6;
  const int lr = lane & 15, lq = lane >> 4;
  const int wm = (wave & 1) * 64, wn = (wave >> 1) * 32;
  const int m0 = blockIdx.y * 128, n0 = blockIdx.x * 64;
  const uint16_t* A = Ob + (size_t)blockIdx.z * sA;
  f32x4 acc[4][2] = {};
  for (int k0 = 0; k0 < K; k0 += 32) {
    __syncthreads();
    for (int p = 0; p < 2; ++p) {
      int u = p * 256 + t;
      int r = u >> 2, c = (u & 3) * 8;
      async16(&A[(size_t)(m0 + r) * K + k0 + c], &At[p * 2048 + wave * 512]);
    }
    {
      int r = t >> 2, c = (t & 3) * 8;
      async16(&Wo[(size_t)(n0 + r) * K + k0 + c], &Bt[wave * 512]);
    }
    __builtin_amdgcn_s_waitcnt(0);
    __syncthreads();
    bf16x8 af[4], bfr[2];
    for (int i = 0; i < 4; ++i)
      af[i] = *(const bf16x8*)&At[(wm + i * 16 + lr) * 32 + lq * 8];
    for (int j = 0; j < 2; ++j)
      bfr[j] = *(const bf16x8*)&Bt[(wn + j * 16 + lr) * 32 + lq * 8];
    for (int i = 0; i < 4; ++i)
      for (int j = 0; j < 2; ++j)
        acc[i][j] = __builtin_amdgcn_mfma_f32_16x16x32_bf16(af[i], bfr[j], acc[i][j], 0, 0, 0);
  }
  float* Cf = Y + (size_t)blockIdx.z * sC;
  for (int i = 0; i < 4; ++i)
    for (int j = 0; j < 2; ++j) {
      int row = m0 + wm + i * 16 + lq * 4;  // s (contiguous)
      int col = n0 + wn + j * 16 + lr;      // c
      float bb = bias[col];
      float4 o = {acc[i][j][0] + bb, acc[i][j][1] + bb,
                  acc[i][j][2] + bb, acc[i][j][3] + bb};
      *(float4*)&Cf[(size_t)col * 4096 + row] = o;
    }
}

// ---------------------------------------------------------------------------
// Flash attention half-range pass, K/V double-buffered. Q pre-scaled.
// 512 threads = 8 waves, q-tile 256. grid (S/256, 8, 4): z = jh*2 + b.
// One waitcnt(0)+barrier per j-iter; next tile's DMA flies across compute.
// Writes UNNORMALIZED partial O^T (bf16) + partial l (fp32).
// K/V LDS tiles XOR-chunk-swizzled: 16B chunk c of row r stored at c^(r&7).
// LDS: Kl 16K + Vl 16K + Pl 36K = 68 KB -> 2 blocks/CU.
// ---------------------------------------------------------------------------
__global__ __launch_bounds__(512, 4) void attn128(
    const uint16_t* __restrict__ Q, const uint16_t* __restrict__ K,
    const uint16_t* __restrict__ Vt, uint16_t* __restrict__ Ap,
    float* __restrict__ Lp) {
  constexpr int S = 4096, E = 512;
  const int b = blockIdx.z & 1, jh = blockIdx.z >> 1;
  const int h = blockIdx.y;
  const int i0 = blockIdx.x * 256;
  const int t = threadIdx.x, lane = t & 63, wave = t >> 6;
  const int lr = lane & 15, lq = lane >> 4;
  const size_t qkB = (size_t)b * S * E;
  const size_t vB = (size_t)b * E * S;
  __shared__ uint16_t Kl[2][64 * 64];     // [buf][j][d], chunk-swizzled rows
  __shared__ uint16_t Vl[2][64 * 64];     // [buf][d][j], chunk-swizzled rows
  __shared__ __bf16 Pl[8 * 2 * 16 * 72];  // [wave][g][i 16][j 64+8pad]

  const int qbase = i0 + wave * 32;
  bf16x8 qf[2][2];
  for (int g = 0; g < 2; ++g) {
    const size_t qo = qkB + (size_t)(qbase + g * 16 + lr) * E + h * 64 + lq * 8;
    qf[g][0] = *(const bf16x8*)&Q[qo];
    qf[g][1] = *(const bf16x8*)&Q[qo + 32];
  }
  f32x4 lsum[2] = {};
  f32x4 accOT[2][4] = {};
  const int swz = (lr & 7);
  const int srr = t >> 3, ssc = ((t & 7) ^ (srr & 7)) * 8;  // staging row/col

  const int jbeg = jh * (S / 2), jend = jbeg + S / 2;
  // prolog: stage first K/V tile into buffer 0
  async16(&K[qkB + (size_t)(jbeg + srr) * E + h * 64 + ssc], &Kl[0][wave * 512]);
  async16(&Vt[vB + (size_t)(h * 64 + srr) * S + jbeg + ssc], &Vl[0][wave * 512]);
  __builtin_amdgcn_s_waitcnt(0);
  __syncthreads();

  int cur = 0;
  for (int j0 = jbeg; j0 < jend; j0 += 64) {
    // stage next tile into the alternate buffer — flies across this compute
    if (j0 + 64 < jend) {
      async16(&K[qkB + (size_t)(j0 + 64 + srr) * E + h * 64 + ssc], &Kl[cur ^ 1][wave * 512]);
      async16(&Vt[vB + (size_t)(h * 64 + srr) * S + j0 + 64 + ssc], &Vl[cur ^ 1][wave * 512]);
    }
    const uint16_t* Kc = Kl[cur];
    const uint16_t* Vc = Vl[cur];
    // S^T tile: C[m=j][n=i] = sum_d K[j][d] Q[i][d]; K-frags shared by g
    f32x4 svt[2][4];
    for (int jn = 0; jn < 4; ++jn) {
      const int row = jn * 16 + lr;
      const int c0 = (lq ^ swz) * 8;
      bf16x8 ka0 = *(const bf16x8*)&Kc[row * 64 + c0];
      bf16x8 ka1 = *(const bf16x8*)&Kc[row * 64 + (c0 ^ 32)];
      for (int g = 0; g < 2; ++g) {
        f32x4 z = {0.f, 0.f, 0.f, 0.f};
        z = __builtin_amdgcn_mfma_f32_16x16x32_bf16(ka0, qf[g][0], z, 0, 0, 0);
        z = __builtin_amdgcn_mfma_f32_16x16x32_bf16(ka1, qf[g][1], z, 0, 0, 0);
        svt[g][jn] = z;
      }
    }
    // P = exp2(s), accumulate l; write BOTH g's P to per-g regions, then read
    for (int g = 0; g < 2; ++g) {
      __bf16* pr = &Pl[((wave * 2 + g) * 16 + lr) * 72];
      for (int jn = 0; jn < 4; ++jn) {
        f32x4 p;
        for (int r = 0; r < 4; ++r) p[r] = exp2f(svt[g][jn][r]);
        lsum[g] += p;
        bf16x4 pk;
        for (int r = 0; r < 4; ++r) pk[r] = (__bf16)p[r];
        *(bf16x4*)&pr[jn * 16 + lq * 4] = pk;
      }
    }
    bf16x8 pa[2][2];
    for (int g = 0; g < 2; ++g) {
      const __bf16* pr = &Pl[((wave * 2 + g) * 16 + lr) * 72];
      pa[g][0] = *(const bf16x8*)&pr[lq * 8];
      pa[g][1] = *(const bf16x8*)&pr[32 + lq * 8];
    }
    // PV in O^T form: A = Vt rows d (k=j), B = P rows i (k=j)
    for (int dn = 0; dn < 4; ++dn) {
      const int row = dn * 16 + lr;
      const int c0 = (lq ^ swz) * 8;
      bf16x8 v0 = *(const bf16x8*)&Vc[row * 64 + c0];
      bf16x8 v1 = *(const bf16x8*)&Vc[row * 64 + (c0 ^ 32)];
      for (int g = 0; g < 2; ++g) {
        accOT[g][dn] = __builtin_amdgcn_mfma_f32_16x16x32_bf16(v0, pa[g][0], accOT[g][dn], 0, 0, 0);
        accOT[g][dn] = __builtin_amdgcn_mfma_f32_16x16x32_bf16(v1, pa[g][1], accOT[g][dn], 0, 0, 0);
      }
    }
    // drain next-tile DMA + sync; also orders next iter's Pl writes after
    // this iter's cross-lane Pl reads (compiler fence).
    __builtin_amdgcn_s_waitcnt(0);
    __syncthreads();
    cur ^= 1;
  }
  // epilogue: store partial l (per query row) and unnormalized partial O
  uint16_t* Aph = Ap + (size_t)jh * 2 * S * E;
  float* Lph = Lp + ((size_t)(jh * 2 + b) * 8 + h) * S;
  for (int g = 0; g < 2; ++g) {
    float lt = (lsum[g][0] + lsum[g][1]) + (lsum[g][2] + lsum[g][3]);
    lt += __shfl_xor(lt, 16);
    lt += __shfl_xor(lt, 32);
    if (lane < 16) Lph[qbase + g * 16 + lr] = lt;
    const size_t row = qbase + g * 16 + lr;
    for (int dn = 0; dn < 4; ++dn) {
      u16x4 o;
      for (int r = 0; r < 4; ++r) o[r] = f2bf(accOT[g][dn][r]);
      *(u16x4*)&Aph[qkB + row * E + h * 64 + dn * 16 + lq * 4] = o;
    }
  }
}

// ---------------------------------------------------------------------------
// Combine: Ob[b][s][e] = (A0+A1) / (l0+l1). 4 elems/thread.
// ---------------------------------------------------------------------------
__global__ __launch_bounds__(256) void attn_combine(
    const uint16_t* __restrict__ Ap, const float* __restrict__ Lp,
    uint16_t* __restrict__ Ob) {
  constexpr int S = 4096, E = 512;
  const size_t HALF = (size_t)2 * S * E;
  const size_t idx = ((size_t)blockIdx.x * 256 + threadIdx.x) * 4;
  const int b = (int)(idx / ((size_t)S * E));
  const size_t rem = idx % ((size_t)S * E);
  const int s = (int)(rem / E), e = (int)(rem % E);
  const int h = e >> 6;
  const float l0 = Lp[((size_t)(0 * 2 + b) * 8 + h) * S + s];
  const float l1 = Lp[((size_t)(1 * 2 + b) * 8 + h) * S + s];
  const float inv = 1.f / (l0 + l1);
  u16x4 a0 = *(const u16x4*)&Ap[idx];
  u16x4 a1 = *(const u16x4*)&Ap[HALF + idx];
  u16x4 o;
  for (int r = 0; r < 4; ++r) o[r] = f2bf((bf2f(a0[r]) + bf2f(a1[r])) * inv);
  *(u16x4*)&Ob[idx] = o;
}

// ---------------------------------------------------------------------------
extern "C" void kernel_launch(void* const* d_in, const int* in_sizes, int n_in,
                              void* d_out, int out_size, void* d_ws, size_t ws_size,
                              hipStream_t stream) {
  const float* x   = (const float*)d_in[0];
  const float* ctx = (const float*)d_in[1];
  const float* Wq  = (const float*)d_in[2];
  const float* bq  = (const float*)d_in[3];
  const float* Wk  = (const float*)d_in[4];
  const float* bk  = (const float*)d_in[5];
  const float* Wv  = (const float*)d_in[6];
  const float* bv  = (const float*)d_in[7];
  const float* Wo  = (const float*)d_in[8];
  const float* bo  = (const float*)d_in[9];
  float* out = (float*)d_out;

  const size_t SZ = (size_t)2 * 4096 * 512;
  uint16_t* xT = (uint16_t*)d_ws;
  uint16_t* cT = xT + SZ;
  uint16_t* Qb = cT + SZ;
  uint16_t* Kb = Qb + SZ;
  uint16_t* Vb = Kb + SZ;    // Vt layout [B][E][S]
  uint16_t* Ob = Vb + SZ;    // attention out [B][S][E]
  uint16_t* Wqb = Ob + SZ;
  uint16_t* Wkb = Wqb + 512 * 512;
  uint16_t* Wvb = Wkb + 512 * 512;
  uint16_t* Wob = Wvb + 512 * 512;
  uint16_t* Ap  = Wob + 512 * 512;            // partial O, [2][B][S][E] bf16
  float*    Lp  = (float*)(Ap + 2 * SZ);      // partial l, [2][B][8][S] fp32
  const long long sIn = 4096LL * 512LL;
  const float slh = 0.125f * 1.44269504088896f;  // SCALE * log2(e)

  cvt_w<<<dim3(256, 4), 256, 0, stream>>>(Wq, Wk, Wv, Wo, Wqb, Wkb, Wvb, Wob);
  transpose_cs<<<dim3(64, 8, 4), 256, 0, stream>>>(x, ctx, xT, cT);
  // fused Q,K,V projections (m/n swapped for vector stores); Q pre-scaled
  QkvArgs qkv = {
      {Wqb, Wkb, cT}, {0, 0, sIn},          // A
      {xT, cT, Wvb}, {sIn, sIn, 0},         // B
      {Qb, Kb, Vb}, {sIn, sIn, sIn},        // C
      {bq, bk, bv},
      {slh, 1.f, 1.f},
      {512, 512, 4096},                      // ldC
      {5, 5, 2},                             // lx = log2(n-tiles)
      {1, 1, 0}};                            // brow
  gemm_qkv<<<dim3(128, 1, 6), 256, 0, stream>>>(qkv);
  attn128<<<dim3(16, 8, 4), 512, 0, stream>>>(Qb, Kb, Vb, Ap, Lp);
  attn_combine<<<dim3(4096), 256, 0, stream>>>(Ap, Lp, Ob);
  // Y[c][s] = sum_e O[s][e] Wo[c][e] + bo[c]  (A=Ob m=s, B=Wo n=c)
  gemm_out<<<dim3(8, 32, 2), 256, 0, stream>>>(Ob, sIn, Wob, out, sIn, bo);
}